// Round 1
// baseline (2001.020 us; speedup 1.0000x reference)
//
#include <hip/hip_runtime.h>
#include <math.h>

#define G_    64
#define N_    512
#define H_    64
#define NT_   32768
#define ET_   1048576
#define EPG_  16384      // edges per graph
#define KP_   359
#define NP2_  22976
#define FIN_  128
#define CPB_  8          // channels per edge-scatter block
#define NCH_  (H_/CPB_)  // 8 channel chunks

// ---------------- e = coords @ pos_W + pos_b ----------------
__global__ void k_e(const float* __restrict__ coords, const float* __restrict__ posW,
                    const float* __restrict__ posb, float* __restrict__ e) {
    int gid = blockIdx.x * 256 + threadIdx.x;     // NT*64 threads
    int n = gid >> 6, c = gid & 63;
    float s = posb[c]
            + coords[n*3+0] * posW[0*64+c]
            + coords[n*3+1] * posW[1*64+c]
            + coords[n*3+2] * posW[2*64+c];
    e[gid] = s;
}

// ---------------- dual GEMM: outA = in@Wa, outB = in@Wb + bias ----------------
__global__ void k_gemm_dual(const float* __restrict__ in, int K,
                            const float* __restrict__ Wa, const float* __restrict__ Wb,
                            const float* __restrict__ bias,
                            float* __restrict__ outA, float* __restrict__ outB) {
    __shared__ float inT[16 * FIN_];
    int row0 = blockIdx.x * 16;
    int t = threadIdx.x;
    for (int idx = t; idx < 16 * K; idx += 256) inT[idx] = in[row0 * K + idx];
    __syncthreads();
    int c = t & 63, rb = t >> 6;
    for (int rr = 0; rr < 4; rr++) {
        int r = rb * 4 + rr;
        float accA = 0.f, accB = bias[c];
        const float* ip = inT + r * K;
        for (int k = 0; k < K; k++) {
            float a = ip[k];
            accA += a * Wa[k*64 + c];
            accB += a * Wb[k*64 + c];
        }
        outA[(row0 + r)*64 + c] = accA;
        outB[(row0 + r)*64 + c] = accB;
    }
}

// ---------------- stage-1 fused edge scatter (Ae, agg, deg) ----------------
// Ae[row] += ea * e[col];  agg[col] += y[row];  deg[col] += 1
__global__ void k_edge1(const int* __restrict__ row, const int* __restrict__ col,
                        const float* __restrict__ ea, const float* __restrict__ e,
                        const float* __restrict__ y,
                        float* __restrict__ Ae, float* __restrict__ agg,
                        float* __restrict__ deg) {
    __shared__ float AeT[N_ * CPB_];
    __shared__ float agT[N_ * CPB_];
    __shared__ float dgT[N_];
    int chunk = blockIdx.x, g = blockIdx.y, t = threadIdx.x;
    for (int i = t; i < N_ * CPB_; i += 256) { AeT[i] = 0.f; agT[i] = 0.f; }
    if (chunk == 0) for (int i = t; i < N_; i += 256) dgT[i] = 0.f;
    __syncthreads();
    int c = t & (CPB_ - 1), slot = t >> 3, c0 = chunk * CPB_;
    int ebase = g * EPG_;
    for (int bi = slot; bi < EPG_; bi += 32) {
        int i  = ebase + bi;
        int r  = row[i], cl = col[i];
        float w = ea[i];
        int rl = r & (N_ - 1), cll = cl & (N_ - 1);
        atomicAdd(&AeT[rl  * CPB_ + c], w * e[cl*64 + c0 + c]);
        atomicAdd(&agT[cll * CPB_ + c], y[r*64 + c0 + c]);
        if (chunk == 0 && c == 0) atomicAdd(&dgT[cll], 1.0f);
    }
    __syncthreads();
    int nbase = g * N_;
    for (int i = t; i < N_ * CPB_; i += 256) {
        int n = i / CPB_, cc = i % CPB_;
        Ae [(nbase + n)*64 + c0 + cc] = AeT[i];
        agg[(nbase + n)*64 + c0 + cc] = agT[i];
    }
    if (chunk == 0) for (int i = t; i < N_; i += 256) deg[nbase + i] = dgT[i];
}

// ---------------- per-node matvec: out[n,h] = sum_d Bk[cls[n]][h,d] * in[n,d] ----------------
__global__ void k_bkmv(const float* __restrict__ in, const int* __restrict__ cls,
                       const float* __restrict__ Bk, float* __restrict__ out) {
    __shared__ float inT[4 * 64];
    int node0 = blockIdx.x * 4;
    int t = threadIdx.x;
    inT[t] = in[node0 * 64 + t];
    __syncthreads();
    int c = t & 63, nb = t >> 6;
    int node = node0 + nb;
    const float* B  = Bk + cls[node] * 4096 + c * 64;
    const float* hv = inT + nb * 64;
    float acc = 0.f;
    #pragma unroll 8
    for (int d = 0; d < 64; d++) acc += B[d] * hv[d];
    out[node*64 + c] = acc;
}

// ---------------- propagate: out[n,i] = sum_j Bk[i,j]*(inA+inB)[n,j] + delta[n,i]*sum_j (inA+inB)[n,j]
__global__ void k_prop(const float* __restrict__ inA, const float* __restrict__ inB,
                       const float* __restrict__ delta, const int* __restrict__ cls,
                       const float* __restrict__ Bk, float* __restrict__ out) {
    __shared__ float hT[4 * 64];
    int node0 = blockIdx.x * 4;
    int t = threadIdx.x;
    float v = inA[node0*64 + t];
    if (inB) v += inB[node0*64 + t];
    hT[t] = v;
    __syncthreads();
    int c = t & 63, nb = t >> 6;
    int node = node0 + nb;
    // threads [nb*64, nb*64+64) are exactly one wave -> shuffle row-sum
    float s = hT[nb*64 + c];
    for (int off = 32; off; off >>= 1) s += __shfl_down(s, off);
    s = __shfl(s, 0);
    const float* B  = Bk + cls[node] * 4096 + c * 64;
    const float* hv = hT + nb * 64;
    float acc = delta[node*64 + c] * s;
    #pragma unroll 8
    for (int d = 0; d < 64; d++) acc += B[d] * hv[d];
    out[node*64 + c] = acc;
}

// ---------------- graph_norm + elu (+ optional delta add): in = hself + agg/max(deg,1) ----------------
__global__ void k_gn(const float* __restrict__ hself, const float* __restrict__ agg,
                     const float* __restrict__ deg,
                     const float* __restrict__ w, const float* __restrict__ b,
                     const float* __restrict__ ms,
                     const float* __restrict__ delta,   // nullable
                     float* __restrict__ out, int NPG) {
    __shared__ float red[4 * 64];
    __shared__ float meanS[64], istdS[64];
    int g = blockIdx.x, t = threadIdx.x;
    int c = t & 63, grp = t >> 6;
    int base = g * NPG;
    float s = 0.f;
    for (int n = grp; n < NPG; n += 4) {
        int node = base + n;
        s += hself[node*64 + c] + agg[node*64 + c] / fmaxf(deg[node], 1.0f);
    }
    red[t] = s;
    __syncthreads();
    if (grp == 0) meanS[c] = (red[c] + red[64+c] + red[128+c] + red[192+c]) / (float)NPG;
    __syncthreads();
    float mval = meanS[c] * ms[c];
    s = 0.f;
    for (int n = grp; n < NPG; n += 4) {
        int node = base + n;
        float v = hself[node*64 + c] + agg[node*64 + c] / fmaxf(deg[node], 1.0f) - mval;
        s += v * v;
    }
    red[t] = s;
    __syncthreads();
    if (grp == 0) {
        float var = (red[c] + red[64+c] + red[128+c] + red[192+c]) / (float)NPG;
        istdS[c] = rsqrtf(var + 1e-5f);
    }
    __syncthreads();
    float wv = w[c], bv = b[c], istd = istdS[c];
    for (int n = grp; n < NPG; n += 4) {
        int node = base + n;
        float v = hself[node*64 + c] + agg[node*64 + c] / fmaxf(deg[node], 1.0f) - mval;
        v = wv * v * istd + bv;
        v = v > 0.f ? v : expm1f(v);
        if (delta) v += delta[node*64 + c];
        out[node*64 + c] = v;
    }
}

// ---------------- top-k per graph (exact jax semantics: desc score, ties by lower idx) ----------------
__global__ void k_topk(const float* __restrict__ hp, const float* __restrict__ p,
                       const int* __restrict__ cls,
                       int* __restrict__ perm, float* __restrict__ tanhv,
                       int* __restrict__ node_map, int* __restrict__ class2) {
    __shared__ float key[N_];
    __shared__ int   idxS[N_];
    __shared__ float pS[64];
    __shared__ float nrm;
    int g = blockIdx.x, t = threadIdx.x;
    if (t < 64) pS[t] = p[t];
    __syncthreads();
    if (t == 0) {
        float s = 0.f;
        for (int i = 0; i < 64; i++) s += pS[i] * pS[i];
        nrm = sqrtf(s);
    }
    __syncthreads();
    {
        float acc = 0.f;
        const float* hv = hp + (size_t)(g*N_ + t) * 64;
        for (int cdx = 0; cdx < 64; cdx++) acc += hv[cdx] * pS[cdx];
        key[t]  = acc / nrm;
        idxS[t] = t;
    }
    __syncthreads();
    for (int k = 2; k <= N_; k <<= 1) {
        for (int j = k >> 1; j > 0; j >>= 1) {
            int i = t, ixj = i ^ j;
            if (ixj > i) {
                float ki = key[i], kj = key[ixj];
                int   ii = idxS[i], ij = idxS[ixj];
                bool before = (ki > kj) || (ki == kj && ii < ij);   // i precedes ixj in desc order
                bool dir = ((i & k) == 0);
                if (dir ? !before : before) {
                    key[i] = kj; key[ixj] = ki;
                    idxS[i] = ij; idxS[ixj] = ii;
                }
            }
            __syncthreads();
        }
    }
    if (t < KP_) {
        int orig  = idxS[t];
        int gnode = g * N_ + orig;
        int pj    = g * KP_ + t;
        perm[pj]     = gnode;
        tanhv[pj]    = tanhf(key[t]);
        node_map[gnode] = pj;
        class2[pj]   = cls[gnode];
    }
}

// ---------------- pooled gather: h2[j] = hp[perm[j]] * tanhv[j] ----------------
__global__ void k_gather(const float* __restrict__ hp, const int* __restrict__ perm,
                         const float* __restrict__ tanhv, float* __restrict__ h2) {
    int gid = blockIdx.x * 256 + threadIdx.x;   // NP2*64
    int j = gid >> 6, c = gid & 63;
    h2[gid] = hp[perm[j]*64 + c] * tanhv[j];
}

// ---------------- stage-2 Ae2 scatter: Ae2[s2] += e[col]  (valid edges) ----------------
__global__ void k_edge2a(const int* __restrict__ row, const int* __restrict__ col,
                         const int* __restrict__ node_map, const float* __restrict__ e,
                         float* __restrict__ Ae2) {
    __shared__ float AeT[KP_ * CPB_];
    int chunk = blockIdx.x, g = blockIdx.y, t = threadIdx.x;
    for (int i = t; i < KP_ * CPB_; i += 256) AeT[i] = 0.f;
    __syncthreads();
    int c = t & (CPB_ - 1), slot = t >> 3, c0 = chunk * CPB_;
    int ebase = g * EPG_, pbase = g * KP_;
    for (int bi = slot; bi < EPG_; bi += 32) {
        int i  = ebase + bi;
        int s2 = node_map[row[i]];
        int t2 = node_map[col[i]];
        if (s2 >= 0 && t2 >= 0)
            atomicAdd(&AeT[(s2 - pbase)*CPB_ + c], e[col[i]*64 + c0 + c]);
    }
    __syncthreads();
    for (int i = t; i < KP_ * CPB_; i += 256) {
        int n = i / CPB_, cc = i % CPB_;
        Ae2[(pbase + n)*64 + c0 + cc] = AeT[i];
    }
}

// ---------------- stage-2 agg scatter: agg2[t2] += y2[s2]; deg2[t2] += 1 ----------------
__global__ void k_edge2b(const int* __restrict__ row, const int* __restrict__ col,
                         const int* __restrict__ node_map, const float* __restrict__ y2,
                         float* __restrict__ agg2, float* __restrict__ deg2) {
    __shared__ float agT[KP_ * CPB_];
    __shared__ float dgT[KP_];
    int chunk = blockIdx.x, g = blockIdx.y, t = threadIdx.x;
    for (int i = t; i < KP_ * CPB_; i += 256) agT[i] = 0.f;
    if (chunk == 0) for (int i = t; i < KP_; i += 256) dgT[i] = 0.f;
    __syncthreads();
    int c = t & (CPB_ - 1), slot = t >> 3, c0 = chunk * CPB_;
    int ebase = g * EPG_, pbase = g * KP_;
    for (int bi = slot; bi < EPG_; bi += 32) {
        int i  = ebase + bi;
        int s2 = node_map[row[i]];
        int t2 = node_map[col[i]];
        if (s2 >= 0 && t2 >= 0) {
            atomicAdd(&agT[(t2 - pbase)*CPB_ + c], y2[s2*64 + c0 + c]);
            if (chunk == 0 && c == 0) atomicAdd(&dgT[t2 - pbase], 1.0f);
        }
    }
    __syncthreads();
    for (int i = t; i < KP_ * CPB_; i += 256) {
        int n = i / CPB_, cc = i % CPB_;
        agg2[(pbase + n)*64 + c0 + cc] = agT[i];
    }
    if (chunk == 0) for (int i = t; i < KP_; i += 256) deg2[pbase + i] = dgT[i];
}

// ---------------- readout: mean/max/sum -> lin1 relu -> lin2 -> log_softmax ----------------
__global__ void k_readout(const float* __restrict__ h3,
                          const float* __restrict__ l1W, const float* __restrict__ l1b,
                          const float* __restrict__ l2W, const float* __restrict__ l2b,
                          float* __restrict__ out) {
    __shared__ float sred[4 * 64], mred[4 * 64];
    __shared__ float gv[192];
    __shared__ float rS[64];
    int g = blockIdx.x, t = threadIdx.x;
    int c = t & 63, grp = t >> 6;
    int base = g * KP_;
    float s = 0.f, m = -1e30f;
    for (int n = grp; n < KP_; n += 4) {
        float v = h3[(base + n)*64 + c];
        s += v; m = fmaxf(m, v);
    }
    sred[t] = s; mred[t] = m;
    __syncthreads();
    if (grp == 0) {
        float ss = sred[c] + sred[64+c] + sred[128+c] + sred[192+c];
        float mm = fmaxf(fmaxf(mred[c], mred[64+c]), fmaxf(mred[128+c], mred[192+c]));
        gv[c]       = ss / (float)KP_;
        gv[64 + c]  = mm;
        gv[128 + c] = ss;
    }
    __syncthreads();
    if (t < 64) {
        float acc = l1b[t];
        for (int k = 0; k < 192; k++) acc += gv[k] * l1W[k*64 + t];
        rS[t] = fmaxf(acc, 0.f);
    }
    __syncthreads();
    if (t == 0) {
        float l0 = l2b[0], l1v = l2b[1];
        for (int hh = 0; hh < 64; hh++) { l0 += rS[hh]*l2W[hh*2+0]; l1v += rS[hh]*l2W[hh*2+1]; }
        float mx  = fmaxf(l0, l1v);
        float lse = mx + logf(expf(l0 - mx) + expf(l1v - mx));
        out[g*2 + 0] = l0  - lse;
        out[g*2 + 1] = l1v - lse;
    }
}

extern "C" void kernel_launch(void* const* d_in, const int* in_sizes, int n_in,
                              void* d_out, int out_size, void* d_ws, size_t ws_size,
                              hipStream_t stream) {
    const float* x      = (const float*)d_in[0];
    const int*   eidx   = (const int*)  d_in[1];
    const float* eattr  = (const float*)d_in[2];
    const float* coords = (const float*)d_in[3];
    const int*   acls   = (const int*)  d_in[4];
    const float* BkT    = (const float*)d_in[5];
    const float* posW   = (const float*)d_in[6];
    const float* posb   = (const float*)d_in[7];
    const float* W1s    = (const float*)d_in[8];
    const float* W1n    = (const float*)d_in[9];
    const float* b1     = (const float*)d_in[10];
    const float* gn1w   = (const float*)d_in[11];
    const float* gn1b   = (const float*)d_in[12];
    const float* gn1ms  = (const float*)d_in[13];
    const float* poolp  = (const float*)d_in[14];
    const float* W2s    = (const float*)d_in[15];
    const float* W2n    = (const float*)d_in[16];
    const float* b2     = (const float*)d_in[17];
    const float* gn2w   = (const float*)d_in[18];
    const float* gn2b   = (const float*)d_in[19];
    const float* gn2ms  = (const float*)d_in[20];
    const float* l1W    = (const float*)d_in[21];
    const float* l1b    = (const float*)d_in[22];
    const float* l2W    = (const float*)d_in[23];
    const float* l2b    = (const float*)d_in[24];

    const int* row  = eidx;
    const int* colp = eidx + ET_;

    float* W = (float*)d_ws;
    const size_t NTH = (size_t)NT_ * 64;
    float* e_buf = W;              // e            (live whole stage 1 + edge2a)
    float* r1    = W + 1*NTH;      // Ae -> hp -> hs2
    float* r2    = W + 2*NTH;      // delta -> delta2 -> h3
    float* r3    = W + 3*NTH;      // hself -> h2 -> agg2
    float* r4    = W + 4*NTH;      // y -> hb -> hp2
    float* r5    = W + 5*NTH;      // agg -> Ae2
    float* small = W + 6*NTH;
    float* deg   = small;                                   // NT floats (reused as deg2)
    float* tanhv = small + NT_;                             // NP2 floats
    int*   perm  = (int*)(small + NT_ + NP2_);              // NP2 ints
    int*   nmap  = (int*)(small + NT_ + 2*NP2_);            // NT ints
    int*   cls2  = (int*)(small + 2*NT_ + 2*NP2_);          // NP2 ints

    // ---- stage 1 ----
    k_e        <<<NT_*64/256, 256, 0, stream>>>(coords, posW, posb, e_buf);
    k_gemm_dual<<<NT_/16,     256, 0, stream>>>(x, FIN_, W1n, W1s, b1, r4 /*y*/, r3 /*hself*/);
    k_edge1    <<<dim3(NCH_, G_), 256, 0, stream>>>(row, colp, eattr, e_buf, r4,
                                                    r1 /*Ae*/, r5 /*agg*/, deg);
    k_bkmv     <<<NT_/4,      256, 0, stream>>>(r1 /*Ae*/, acls, BkT, r2 /*delta*/);
    k_gn       <<<G_,         256, 0, stream>>>(r3 /*hself*/, r5 /*agg*/, deg,
                                                gn1w, gn1b, gn1ms, r2 /*+delta*/,
                                                r4 /*hb*/, N_);
    k_prop     <<<NT_/4,      256, 0, stream>>>(r4 /*hb*/, nullptr, r2 /*delta*/, acls, BkT,
                                                r1 /*hp*/);
    hipMemsetAsync(nmap, 0xFF, NT_ * sizeof(int), stream);
    k_topk     <<<G_,         512, 0, stream>>>(r1 /*hp*/, poolp, acls, perm, tanhv, nmap, cls2);
    k_gather   <<<NP2_*64/256,256, 0, stream>>>(r1 /*hp*/, perm, tanhv, r3 /*h2*/);

    // ---- stage 2 ----
    k_edge2a   <<<dim3(NCH_, G_), 256, 0, stream>>>(row, colp, nmap, e_buf, r5 /*Ae2*/);
    k_bkmv     <<<NP2_/4,     256, 0, stream>>>(r5 /*Ae2*/, cls2, BkT, r2 /*delta2*/);
    k_prop     <<<NP2_/4,     256, 0, stream>>>(r3 /*h2*/, r2 /*delta2*/, r2 /*delta2*/, cls2, BkT,
                                                r4 /*hp2*/);
    k_gemm_dual<<<NP2_/16,    256, 0, stream>>>(r4 /*hp2*/, 64, W2n, W2s, b2,
                                                e_buf /*y2*/, r1 /*hs2*/);
    k_edge2b   <<<dim3(NCH_, G_), 256, 0, stream>>>(row, colp, nmap, e_buf /*y2*/,
                                                    r3 /*agg2*/, deg /*deg2*/);
    k_gn       <<<G_,         256, 0, stream>>>(r1 /*hs2*/, r3 /*agg2*/, deg /*deg2*/,
                                                gn2w, gn2b, gn2ms, nullptr,
                                                r2 /*h3*/, KP_);
    k_readout  <<<G_,         256, 0, stream>>>(r2 /*h3*/, l1W, l1b, l2W, l2b, (float*)d_out);
}